// Round 6
// baseline (424.175 us; speedup 1.0000x reference)
//
#include <hip/hip_runtime.h>
#include <stdint.h>
#include <stddef.h>

#define Tq 2048
#define DM 1024

typedef unsigned short u16;
typedef __bf16 bf16x8 __attribute__((ext_vector_type(8)));
typedef float f32x4 __attribute__((ext_vector_type(4)));
typedef unsigned short u16x8 __attribute__((ext_vector_type(8)));

__device__ __forceinline__ float bf2f(u16 h) {
    union { unsigned int u; float f; } c; c.u = ((unsigned int)h) << 16; return c.f;
}
__device__ __forceinline__ u16 f2bf(float f) {
    union { float f; unsigned int u; } c; c.f = f;
    unsigned int u = c.u;
    return (u16)((u + 0x7fffu + ((u >> 16) & 1u)) >> 16);  // RNE
}

// async global->LDS, 16B per lane; lds base wave-uniform (HW adds lane*16)
#define GLD(gp, lp) __builtin_amdgcn_global_load_lds(                                  \
        (const __attribute__((address_space(1))) void*)(gp),                           \
        (__attribute__((address_space(3))) void*)(lp), 16, 0, 0)

// ---------------------------------------------------------------------------
// Format sniff (round-3 proven).
// ---------------------------------------------------------------------------
__device__ __forceinline__ int sniff_fp32(const u16* xs) {
    const int lane = threadIdx.x & 63;
    const u16 u = xs[lane];
    const int e = (u >> 7) & 0xFF;
    unsigned long long m = __ballot(e >= 160);
    return __popcll(m) >= 4;
}

__device__ __forceinline__ void cvt_body(const void* src, u16* dst, int i0, int fmt) {
    if (fmt) {
        const float* s = (const float*)src;
        float4 a = *(const float4*)(s + i0);
        float4 b = *(const float4*)(s + i0 + 4);
        u16x8 o;
        o[0] = f2bf(a.x); o[1] = f2bf(a.y); o[2] = f2bf(a.z); o[3] = f2bf(a.w);
        o[4] = f2bf(b.x); o[5] = f2bf(b.y); o[6] = f2bf(b.z); o[7] = f2bf(b.w);
        *(u16x8*)(dst + i0) = o;
    } else {
        *(u16x8*)(dst + i0) = *(const u16x8*)((const u16*)src + i0);
    }
}

__global__ void cvt_tensor(const void* __restrict__ src, u16* __restrict__ dst, int n,
                           const u16* __restrict__ xs, int* flag, int writeflag) {
    const int fmt = sniff_fp32(xs);
    if (writeflag && blockIdx.x == 0 && threadIdx.x == 0) *flag = fmt;
    const int i0 = (blockIdx.x * 256 + threadIdx.x) * 8;
    if (i0 >= n) return;
    cvt_body(src, dst, i0, fmt);
}

// All four weight matrices in one launch: grid (512, 4)
__global__ void cvt_w4(const void* s0, const void* s1, const void* s2, const void* s3,
                       u16* __restrict__ dst, const u16* __restrict__ xs) {
    const int fmt = sniff_fp32(xs);
    const int wsel = blockIdx.y;
    const void* s = (wsel == 0) ? s0 : (wsel == 1) ? s1 : (wsel == 2) ? s2 : s3;
    u16* d = dst + (size_t)wsel * (DM * DM);
    const int i0 = (blockIdx.x * 256 + threadIdx.x) * 8;
    cvt_body(s, d, i0, fmt);
}

// All four biases in one launch: grid (4)
__global__ void cvt_b4(const void* s0, const void* s1, const void* s2, const void* s3,
                       float* __restrict__ dst, const u16* __restrict__ xs) {
    const int fmt = sniff_fp32(xs);
    const int bsel = blockIdx.x;
    const void* s = (bsel == 0) ? s0 : (bsel == 1) ? s1 : (bsel == 2) ? s2 : s3;
    float* d = dst + (size_t)bsel * DM;
    const int i0 = threadIdx.x * 4;
    if (fmt) {
        *(float4*)(d + i0) = *(const float4*)((const float*)s + i0);
    } else {
        const u16* ss = (const u16*)s;
        d[i0+0] = bf2f(ss[i0+0]); d[i0+1] = bf2f(ss[i0+1]);
        d[i0+2] = bf2f(ss[i0+2]); d[i0+3] = bf2f(ss[i0+3]);
    }
}

// ---------------------------------------------------------------------------
// GEMM, m97 structure (unchanged from round 5 — known good).
// ---------------------------------------------------------------------------
__global__ __launch_bounds__(256, 2) void gemm_bt(
    const u16* __restrict__ A,
    const u16* __restrict__ W0, const u16* __restrict__ W1, const u16* __restrict__ W2,
    const float* __restrict__ b0, const float* __restrict__ b1, const float* __restrict__ b2,
    u16* o0, u16* o1, u16* o2,
    const int* __restrict__ flag, int mode)
{
    __shared__ u16 Alds[128 * 64];
    __shared__ u16 Blds[128 * 64];

    const int K = DM;
    const int i = blockIdx.x;
    const int j = blockIdx.y;
    const int which = (mode == 0) ? (j >> 3) : 0;
    const u16* W      = (which == 0) ? W0 : (which == 1) ? W1 : W2;
    const float* bias = (which == 0) ? b0 : (which == 1) ? b1 : b2;
    u16* out          = (which == 0) ? o0 : (which == 1) ? o1 : o2;
    const int jn = (mode == 0) ? (j & 7) : j;
    const int m0 = i * 128, n0 = jn * 128;
    const int ofmt = (mode == 1) ? *flag : 0;

    const int tid = threadIdx.x;
    const int w = tid >> 6, lane = tid & 63;
    const int l4 = lane & 15, quad = lane >> 4;
    const int wrow = w >> 1, wcol = w & 1;

    f32x4 acc[4][4] = {};

    for (int k0 = 0; k0 < K; k0 += 64) {
        __syncthreads();
#pragma unroll
        for (int c = 0; c < 4; ++c) {
            const int u   = w * 1024 + c * 4096;
            const int off = u + lane * 16;
            const int row = off >> 7;
            const int col = (off & 127) >> 1;
            GLD(A + (size_t)(m0 + row) * K + k0 + col, (char*)Alds + u);
            GLD(W + (size_t)(n0 + row) * K + k0 + col, (char*)Blds + u);
        }
        __syncthreads();
#pragma unroll
        for (int c = 0; c < 2; ++c) {
            bf16x8 af[4], bfr[4];
#pragma unroll
            for (int r = 0; r < 4; ++r)
                af[r] = *(const bf16x8*)&Alds[(wrow*64 + r*16 + l4) * 64 + c*32 + quad*8];
#pragma unroll
            for (int n = 0; n < 4; ++n)
                bfr[n] = *(const bf16x8*)&Blds[(wcol*64 + n*16 + l4) * 64 + c*32 + quad*8];
#pragma unroll
            for (int r = 0; r < 4; ++r)
#pragma unroll
                for (int n = 0; n < 4; ++n)
                    acc[r][n] = __builtin_amdgcn_mfma_f32_16x16x32_bf16(af[r], bfr[n], acc[r][n], 0, 0, 0);
        }
    }

#pragma unroll
    for (int n = 0; n < 4; ++n) {
        const int col = n0 + wcol*64 + n*16 + l4;
        const float bv = bias[col];
#pragma unroll
        for (int r = 0; r < 4; ++r) {
            const int mb = m0 + wrow*64 + r*16 + quad*4;
#pragma unroll
            for (int reg = 0; reg < 4; ++reg) {
                const int m = mb + reg;
                const float val = acc[r][n][reg] + bv;
                if (mode == 0) {
                    const int b = m >> 11, t = m & 2047;
                    const int h = col >> 6, d = col & 63;
                    out[(size_t)((b*16 + h) * 2048 + t) * 64 + d] = f2bf(val);
                } else if (ofmt) {
                    ((float*)out)[(size_t)m * DM + col] = val;
                } else {
                    out[(size_t)m * DM + col] = f2bf(val);
                }
            }
        }
    }
}

// ---------------------------------------------------------------------------
// V transpose (unchanged from round 5).
// ---------------------------------------------------------------------------
#define GSTR 72
__global__ __launch_bounds__(256, 4) void vtrans(
    const u16* __restrict__ Vb, u16* __restrict__ VT)
{
    __shared__ u16 T[64 * GSTR];
    const int t0 = blockIdx.x * 64;
    const int bh = blockIdx.y;
    const u16* src = Vb + (size_t)bh * (Tq * 64);
    u16* dst       = VT + (size_t)bh * (64 * Tq);

    const int tid  = threadIdx.x;
    const int trow = tid >> 2;
    const int c16  = (tid & 3) * 16;
    {
        u16x8 a = *(const u16x8*)&src[(size_t)(t0 + trow) * 64 + c16];
        u16x8 b = *(const u16x8*)&src[(size_t)(t0 + trow) * 64 + c16 + 8];
        const int s  = (trow + (trow >> 3)) & 7;
        const int g0 = c16 >> 3;
        *(u16x8*)&T[trow * GSTR + ((g0 ^ s) << 3)]       = a;
        *(u16x8*)&T[trow * GSTR + (((g0 + 1) ^ s) << 3)] = b;
    }
    __syncthreads();
    const int d  = tid >> 2;
    const int j0 = (tid & 3) * 16;
    u16x8 o0, o1;
#pragma unroll
    for (int e = 0; e < 8; ++e) {
        const int ta = j0 + e, tb = j0 + 8 + e;
        const int sa = (ta + (ta >> 3)) & 7, sb = (tb + (tb >> 3)) & 7;
        o0[e] = T[ta * GSTR + ((((d >> 3) ^ sa) << 3) | (d & 7))];
        o1[e] = T[tb * GSTR + ((((d >> 3) ^ sb) << 3) | (d & 7))];
    }
    *(u16x8*)&dst[(size_t)d * Tq + t0 + j0]     = o0;
    *(u16x8*)&dst[(size_t)d * Tq + t0 + j0 + 8] = o1;
}

// ---------------------------------------------------------------------------
// Flash attention v3: shared-fragment MFMA — each kf feeds both tiles' S,
// each vf feeds both tiles' PV (LDS reads/iter 36 -> 20). XCD swizzle kept.
// ---------------------------------------------------------------------------
#define LSTR 72
#define MFMA16(a, b, c) __builtin_amdgcn_mfma_f32_16x16x32_bf16(a, b, c, 0, 0, 0)

__global__ __launch_bounds__(256, 4) void attn2(
    const u16* __restrict__ Qb, const u16* __restrict__ Kb, const u16* __restrict__ VT,
    const unsigned char* __restrict__ pad,
    u16* __restrict__ Y)
{
    __shared__ u16 Klds[64 * LSTR];
    __shared__ u16 Vtl [64 * LSTR];
    __shared__ u16 Pa  [64 * LSTR];
    __shared__ u16 Pb  [64 * LSTR];
    __shared__ unsigned char padl[64];

    const int qa = blockIdx.y;           // 0..15
    const int qb = 31 - qa;
    const int bh = blockIdx.x;           // 0..63 -> XCD = bh % 8
    const int b = bh >> 4, h = bh & 15;
    const u16* Qp  = Qb + (size_t)bh * (Tq * 64);
    const u16* Kp  = Kb + (size_t)bh * (Tq * 64);
    const u16* VTp = VT + (size_t)bh * (64 * Tq);

    const int tid = threadIdx.x;
    const int w = tid >> 6, lane = tid & 63;
    const int l4 = lane & 15, quad = lane >> 4;
    const int q0a = qa * 64, q0b = qb * 64;

    bf16x8 qfa[2], qfb[2];
    {
        const u16* ra = Qp + (size_t)(q0a + w*16 + l4) * 64 + quad*8;
        const u16* rb = Qp + (size_t)(q0b + w*16 + l4) * 64 + quad*8;
        qfa[0] = *(const bf16x8*)ra; qfa[1] = *(const bf16x8*)(ra + 32);
        qfb[0] = *(const bf16x8*)rb; qfb[1] = *(const bf16x8*)(rb + 32);
    }

    f32x4 oa[4] = {}, ob[4] = {};
    float la[4] = {}, lb[4] = {};

    const int srow = tid >> 2;
    const int sc   = (tid & 3) * 16;

    u16x8 kr0, kr1, vr0, vr1; unsigned char pr = 0;
    {
        const u16* kg = Kp + (size_t)srow * 64 + sc;
        kr0 = *(const u16x8*)kg; kr1 = *(const u16x8*)(kg + 8);
        const u16* vg = VTp + (size_t)srow * Tq + sc;
        vr0 = *(const u16x8*)vg; vr1 = *(const u16x8*)(vg + 8);
        if (tid < 64) pr = pad[(size_t)b * Tq + tid];
    }

    const float SC = 0.18033688011112042f;   // log2(e)/sqrt(64)
    const int qra = q0a + w*16 + quad*4;
    const int qrb = q0b + w*16 + quad*4;

    for (int kt = 0; kt <= qb; ++kt) {
        const int k0 = kt * 64;
        const bool actA = (kt <= qa);
        __syncthreads();
        *(u16x8*)&Klds[srow * LSTR + sc]     = kr0;
        *(u16x8*)&Klds[srow * LSTR + sc + 8] = kr1;
        *(u16x8*)&Vtl [srow * LSTR + sc]     = vr0;
        *(u16x8*)&Vtl [srow * LSTR + sc + 8] = vr1;
        if (tid < 64) padl[tid] = pr;
        __syncthreads();
        if (kt < qb) {
            const u16* kg = Kp + (size_t)(k0 + 64 + srow) * 64 + sc;
            kr0 = *(const u16x8*)kg; kr1 = *(const u16x8*)(kg + 8);
            const u16* vg = VTp + (size_t)srow * Tq + k0 + 64 + sc;
            vr0 = *(const u16x8*)vg; vr1 = *(const u16x8*)(vg + 8);
            if (tid < 64) pr = pad[(size_t)b * Tq + k0 + 64 + tid];
        }

        bool pm[4];
#pragma unroll
        for (int n = 0; n < 4; ++n) pm[n] = (padl[n*16 + l4] != 0);

        // ---- S phase: shared kf reads ----
        f32x4 sa[4] = {}, sb[4] = {};
        if (actA) {
#pragma unroll
            for (int c = 0; c < 2; ++c)
#pragma unroll
                for (int n = 0; n < 4; ++n) {
                    bf16x8 kf = *(const bf16x8*)&Klds[(n*16 + l4) * LSTR + c*32 + quad*8];
                    sb[n] = MFMA16(qfb[c], kf, sb[n]);
                    sa[n] = MFMA16(qfa[c], kf, sa[n]);
                }
        } else {
#pragma unroll
            for (int c = 0; c < 2; ++c)
#pragma unroll
                for (int n = 0; n < 4; ++n) {
                    bf16x8 kf = *(const bf16x8*)&Klds[(n*16 + l4) * LSTR + c*32 + quad*8];
                    sb[n] = MFMA16(qfb[c], kf, sb[n]);
                }
        }

        // ---- softmax B ----
#pragma unroll
        for (int r = 0; r < 4; ++r) {
            float rs = 0.f;
#pragma unroll
            for (int n = 0; n < 4; ++n) {
                const int kgi = k0 + n*16 + l4;
                const bool msk = (kgi > qrb + r) || pm[n];
                const float p = msk ? 0.0f : exp2f(sb[n][r] * SC);
                rs += p;
                Pb[(w*16 + quad*4 + r) * LSTR + n*16 + l4] = f2bf(p);
            }
            lb[r] += rs;
        }
        // ---- softmax A ----
        if (actA) {
#pragma unroll
            for (int r = 0; r < 4; ++r) {
                float rs = 0.f;
#pragma unroll
                for (int n = 0; n < 4; ++n) {
                    const int kgi = k0 + n*16 + l4;
                    const bool msk = (kgi > qra + r) || pm[n];
                    const float p = msk ? 0.0f : exp2f(sa[n][r] * SC);
                    rs += p;
                    Pa[(w*16 + quad*4 + r) * LSTR + n*16 + l4] = f2bf(p);
                }
                la[r] += rs;
            }
        }
        __syncthreads();

        // ---- PV phase: shared vf reads ----
        if (actA) {
#pragma unroll
            for (int c = 0; c < 2; ++c) {
                bf16x8 pfb = *(const bf16x8*)&Pb[(w*16 + l4) * LSTR + c*32 + quad*8];
                bf16x8 pfa = *(const bf16x8*)&Pa[(w*16 + l4) * LSTR + c*32 + quad*8];
#pragma unroll
                for (int t = 0; t < 4; ++t) {
                    bf16x8 vf = *(const bf16x8*)&Vtl[(t*16 + l4) * LSTR + c*32 + quad*8];
                    ob[t] = MFMA16(pfb, vf, ob[t]);
                    oa[t] = MFMA16(pfa, vf, oa[t]);
                }
            }
        } else {
#pragma unroll
            for (int c = 0; c < 2; ++c) {
                bf16x8 pfb = *(const bf16x8*)&Pb[(w*16 + l4) * LSTR + c*32 + quad*8];
#pragma unroll
                for (int t = 0; t < 4; ++t) {
                    bf16x8 vf = *(const bf16x8*)&Vtl[(t*16 + l4) * LSTR + c*32 + quad*8];
                    ob[t] = MFMA16(pfb, vf, ob[t]);
                }
            }
        }
    }

#pragma unroll
    for (int r = 0; r < 4; ++r) {
#pragma unroll
        for (int s = 1; s < 16; s <<= 1) {
            la[r] += __shfl_xor(la[r], s);
            lb[r] += __shfl_xor(lb[r], s);
        }
    }
#pragma unroll
    for (int r = 0; r < 4; ++r) {
        const float ia = 1.0f / la[r], ib = 1.0f / lb[r];
        u16* ya = Y + (size_t)(b * Tq + (q0a + w*16 + quad*4 + r)) * DM + h * 64;
        u16* yb = Y + (size_t)(b * Tq + (q0b + w*16 + quad*4 + r)) * DM + h * 64;
#pragma unroll
        for (int t = 0; t < 4; ++t) {
            ya[t*16 + l4] = f2bf(oa[t][r] * ia);
            yb[t*16 + l4] = f2bf(ob[t][r] * ib);
        }
    }
}

// ---------------------------------------------------------------------------
extern "C" void kernel_launch(void* const* d_in, const int* in_sizes, int n_in,
                              void* d_out, int out_size, void* d_ws, size_t ws_size,
                              hipStream_t stream) {
    const void* x  = d_in[0];
    const unsigned char* pad = (const unsigned char*)d_in[1];
    const void* Wq = d_in[2];
    const void* bq = d_in[3];
    const void* Wk = d_in[4];
    const void* bk = d_in[5];
    const void* Wv = d_in[6];
    const void* bv = d_in[7];
    const void* Wo = d_in[8];
    const void* bo = d_in[9];
    const u16* xs = (const u16*)x;

    const size_t NEL = (size_t)8192 * 1024;
    const size_t WEL = (size_t)1024 * 1024;

    int* flag   = (int*)d_ws;
    u16* base16 = (u16*)((char*)d_ws + 256);
    u16* xc     = base16;                          // canonical x; reused as Yb
    u16* Wc     = base16 + NEL;                    // Wq,Wk,Wv,Wo
    float* bf_  = (float*)(base16 + NEL + 4*WEL);  // 4 x 1024 fp32 biases
    u16* Qb     = (u16*)(bf_ + 4096);
    u16* Kb     = Qb + NEL;
    u16* Vb     = Kb + NEL;
    u16* VT     = Vb + NEL;                        // (B,H,64,T)
    u16* Yb     = xc;

    cvt_tensor<<<dim3((int)(NEL/2048)), 256, 0, stream>>>(x, xc, (int)NEL, xs, flag, 1);
    cvt_w4<<<dim3(512, 4), 256, 0, stream>>>(Wq, Wk, Wv, Wo, Wc, xs);
    cvt_b4<<<dim3(4), 256, 0, stream>>>(bq, bk, bv, bo, bf_, xs);

    gemm_bt<<<dim3(64, 24), 256, 0, stream>>>(xc, Wc, Wc + WEL, Wc + 2*WEL,
                                              bf_, bf_ + 1024, bf_ + 2048,
                                              Qb, Kb, Vb, flag, 0);
    vtrans<<<dim3(32, 64), 256, 0, stream>>>(Vb, VT);
    attn2<<<dim3(64, 16), 256, 0, stream>>>(Qb, Kb, VT, pad, Yb);
    gemm_bt<<<dim3(64, 8), 256, 0, stream>>>(Yb, Wc + 3*WEL, Wc + 3*WEL, Wc + 3*WEL,
                                             bf_ + 3072, bf_ + 3072, bf_ + 3072,
                                             (u16*)d_out, nullptr, nullptr, flag, 1);
}

// Round 7
// 361.705 us; speedup vs baseline: 1.1727x; 1.1727x over previous
//
#include <hip/hip_runtime.h>
#include <stdint.h>
#include <stddef.h>

#define Tq 2048
#define DM 1024

typedef unsigned short u16;
typedef __bf16 bf16x8 __attribute__((ext_vector_type(8)));
typedef float f32x4 __attribute__((ext_vector_type(4)));
typedef unsigned short u16x8 __attribute__((ext_vector_type(8)));

__device__ __forceinline__ float bf2f(u16 h) {
    union { unsigned int u; float f; } c; c.u = ((unsigned int)h) << 16; return c.f;
}
__device__ __forceinline__ u16 f2bf(float f) {
    union { float f; unsigned int u; } c; c.f = f;
    unsigned int u = c.u;
    return (u16)((u + 0x7fffu + ((u >> 16) & 1u)) >> 16);  // RNE
}

// async global->LDS, 16B per lane; lds base wave-uniform (HW adds lane*16)
#define GLD(gp, lp) __builtin_amdgcn_global_load_lds(                                  \
        (const __attribute__((address_space(1))) void*)(gp),                           \
        (__attribute__((address_space(3))) void*)(lp), 16, 0, 0)

// ---------------------------------------------------------------------------
// Format sniff (round-3 proven).
// ---------------------------------------------------------------------------
__device__ __forceinline__ int sniff_fp32(const u16* xs) {
    const int lane = threadIdx.x & 63;
    const u16 u = xs[lane];
    const int e = (u >> 7) & 0xFF;
    unsigned long long m = __ballot(e >= 160);
    return __popcll(m) >= 4;
}

__device__ __forceinline__ void cvt_body(const void* src, u16* dst, int i0, int fmt) {
    if (fmt) {
        const float* s = (const float*)src;
        float4 a = *(const float4*)(s + i0);
        float4 b = *(const float4*)(s + i0 + 4);
        u16x8 o;
        o[0] = f2bf(a.x); o[1] = f2bf(a.y); o[2] = f2bf(a.z); o[3] = f2bf(a.w);
        o[4] = f2bf(b.x); o[5] = f2bf(b.y); o[6] = f2bf(b.z); o[7] = f2bf(b.w);
        *(u16x8*)(dst + i0) = o;
    } else {
        *(u16x8*)(dst + i0) = *(const u16x8*)((const u16*)src + i0);
    }
}

__global__ void cvt_tensor(const void* __restrict__ src, u16* __restrict__ dst, int n,
                           const u16* __restrict__ xs, int* flag, int writeflag) {
    const int fmt = sniff_fp32(xs);
    if (writeflag && blockIdx.x == 0 && threadIdx.x == 0) *flag = fmt;
    const int i0 = (blockIdx.x * 256 + threadIdx.x) * 8;
    if (i0 >= n) return;
    cvt_body(src, dst, i0, fmt);
}

// All four weights + all four biases in one launch: grid (512, 4).
__global__ void cvt_w4b(const void* s0, const void* s1, const void* s2, const void* s3,
                        const void* t0, const void* t1, const void* t2, const void* t3,
                        u16* __restrict__ dstW, float* __restrict__ dstB,
                        const u16* __restrict__ xs) {
    const int fmt = sniff_fp32(xs);
    const int wsel = blockIdx.y;
    const void* s = (wsel == 0) ? s0 : (wsel == 1) ? s1 : (wsel == 2) ? s2 : s3;
    u16* d = dstW + (size_t)wsel * (DM * DM);
    const int i0 = (blockIdx.x * 256 + threadIdx.x) * 8;
    cvt_body(s, d, i0, fmt);
    if (blockIdx.x == 0) {                         // bias wsel piggybacked
        const void* bs = (wsel == 0) ? t0 : (wsel == 1) ? t1 : (wsel == 2) ? t2 : t3;
        float* db = dstB + (size_t)wsel * DM;
        const int j0 = threadIdx.x * 4;
        if (fmt) {
            *(float4*)(db + j0) = *(const float4*)((const float*)bs + j0);
        } else {
            const u16* ss = (const u16*)bs;
            db[j0+0] = bf2f(ss[j0+0]); db[j0+1] = bf2f(ss[j0+1]);
            db[j0+2] = bf2f(ss[j0+2]); db[j0+3] = bf2f(ss[j0+3]);
        }
    }
}

// ---------------------------------------------------------------------------
// GEMM, m97 structure (unchanged — known good).
// ---------------------------------------------------------------------------
__global__ __launch_bounds__(256, 2) void gemm_bt(
    const u16* __restrict__ A,
    const u16* __restrict__ W0, const u16* __restrict__ W1, const u16* __restrict__ W2,
    const float* __restrict__ b0, const float* __restrict__ b1, const float* __restrict__ b2,
    u16* o0, u16* o1, u16* o2,
    const int* __restrict__ flag, int mode)
{
    __shared__ u16 Alds[128 * 64];
    __shared__ u16 Blds[128 * 64];

    const int K = DM;
    const int i = blockIdx.x;
    const int j = blockIdx.y;
    const int which = (mode == 0) ? (j >> 3) : 0;
    const u16* W      = (which == 0) ? W0 : (which == 1) ? W1 : W2;
    const float* bias = (which == 0) ? b0 : (which == 1) ? b1 : b2;
    u16* out          = (which == 0) ? o0 : (which == 1) ? o1 : o2;
    const int jn = (mode == 0) ? (j & 7) : j;
    const int m0 = i * 128, n0 = jn * 128;
    const int ofmt = (mode == 1) ? *flag : 0;

    const int tid = threadIdx.x;
    const int w = tid >> 6, lane = tid & 63;
    const int l4 = lane & 15, quad = lane >> 4;
    const int wrow = w >> 1, wcol = w & 1;

    f32x4 acc[4][4] = {};

    for (int k0 = 0; k0 < K; k0 += 64) {
        __syncthreads();
#pragma unroll
        for (int c = 0; c < 4; ++c) {
            const int u   = w * 1024 + c * 4096;
            const int off = u + lane * 16;
            const int row = off >> 7;
            const int col = (off & 127) >> 1;
            GLD(A + (size_t)(m0 + row) * K + k0 + col, (char*)Alds + u);
            GLD(W + (size_t)(n0 + row) * K + k0 + col, (char*)Blds + u);
        }
        __syncthreads();
#pragma unroll
        for (int c = 0; c < 2; ++c) {
            bf16x8 af[4], bfr[4];
#pragma unroll
            for (int r = 0; r < 4; ++r)
                af[r] = *(const bf16x8*)&Alds[(wrow*64 + r*16 + l4) * 64 + c*32 + quad*8];
#pragma unroll
            for (int n = 0; n < 4; ++n)
                bfr[n] = *(const bf16x8*)&Blds[(wcol*64 + n*16 + l4) * 64 + c*32 + quad*8];
#pragma unroll
            for (int r = 0; r < 4; ++r)
#pragma unroll
                for (int n = 0; n < 4; ++n)
                    acc[r][n] = __builtin_amdgcn_mfma_f32_16x16x32_bf16(af[r], bfr[n], acc[r][n], 0, 0, 0);
        }
    }

#pragma unroll
    for (int n = 0; n < 4; ++n) {
        const int col = n0 + wcol*64 + n*16 + l4;
        const float bv = bias[col];
#pragma unroll
        for (int r = 0; r < 4; ++r) {
            const int mb = m0 + wrow*64 + r*16 + quad*4;
#pragma unroll
            for (int reg = 0; reg < 4; ++reg) {
                const int m = mb + reg;
                const float val = acc[r][n][reg] + bv;
                if (mode == 0) {
                    const int b = m >> 11, t = m & 2047;
                    const int h = col >> 6, d = col & 63;
                    out[(size_t)((b*16 + h) * 2048 + t) * 64 + d] = f2bf(val);
                } else if (ofmt) {
                    ((float*)out)[(size_t)m * DM + col] = val;
                } else {
                    out[(size_t)m * DM + col] = f2bf(val);
                }
            }
        }
    }
}

// ---------------------------------------------------------------------------
// V transpose (unchanged).
// ---------------------------------------------------------------------------
#define GSTR 72
__global__ __launch_bounds__(256, 4) void vtrans(
    const u16* __restrict__ Vb, u16* __restrict__ VT)
{
    __shared__ u16 T[64 * GSTR];
    const int t0 = blockIdx.x * 64;
    const int bh = blockIdx.y;
    const u16* src = Vb + (size_t)bh * (Tq * 64);
    u16* dst       = VT + (size_t)bh * (64 * Tq);

    const int tid  = threadIdx.x;
    const int trow = tid >> 2;
    const int c16  = (tid & 3) * 16;
    {
        u16x8 a = *(const u16x8*)&src[(size_t)(t0 + trow) * 64 + c16];
        u16x8 b = *(const u16x8*)&src[(size_t)(t0 + trow) * 64 + c16 + 8];
        const int s  = (trow + (trow >> 3)) & 7;
        const int g0 = c16 >> 3;
        *(u16x8*)&T[trow * GSTR + ((g0 ^ s) << 3)]       = a;
        *(u16x8*)&T[trow * GSTR + (((g0 + 1) ^ s) << 3)] = b;
    }
    __syncthreads();
    const int d  = tid >> 2;
    const int j0 = (tid & 3) * 16;
    u16x8 o0, o1;
#pragma unroll
    for (int e = 0; e < 8; ++e) {
        const int ta = j0 + e, tb = j0 + 8 + e;
        const int sa = (ta + (ta >> 3)) & 7, sb = (tb + (tb >> 3)) & 7;
        o0[e] = T[ta * GSTR + ((((d >> 3) ^ sa) << 3) | (d & 7))];
        o1[e] = T[tb * GSTR + ((((d >> 3) ^ sb) << 3) | (d & 7))];
    }
    *(u16x8*)&dst[(size_t)d * Tq + t0 + j0]     = o0;
    *(u16x8*)&dst[(size_t)d * Tq + t0 + j0 + 8] = o1;
}

// ---------------------------------------------------------------------------
// Flash attention v2 — EXACT round-5 version (160 µs, no spill). Round-6's
// fragment hoisting made sa+sb / pfa+pfb simultaneously live -> scratch
// spill (+175 MB WRITE). Do not hoist without raising the register budget.
// ---------------------------------------------------------------------------
#define LSTR 72

__global__ __launch_bounds__(256, 4) void attn2(
    const u16* __restrict__ Qb, const u16* __restrict__ Kb, const u16* __restrict__ VT,
    const unsigned char* __restrict__ pad,
    u16* __restrict__ Y)
{
    __shared__ u16 Klds[64 * LSTR];
    __shared__ u16 Vtl [64 * LSTR];
    __shared__ u16 Pa  [64 * LSTR];
    __shared__ u16 Pb  [64 * LSTR];
    __shared__ unsigned char padl[64];

    const int qa = blockIdx.y;           // 0..15
    const int qb = 31 - qa;
    const int bh = blockIdx.x;           // 0..63 -> XCD = bh % 8
    const int b = bh >> 4, h = bh & 15;
    const u16* Qp  = Qb + (size_t)bh * (Tq * 64);
    const u16* Kp  = Kb + (size_t)bh * (Tq * 64);
    const u16* VTp = VT + (size_t)bh * (64 * Tq);

    const int tid = threadIdx.x;
    const int w = tid >> 6, lane = tid & 63;
    const int l4 = lane & 15, quad = lane >> 4;
    const int q0a = qa * 64, q0b = qb * 64;

    bf16x8 qfa[2], qfb[2];
    {
        const u16* ra = Qp + (size_t)(q0a + w*16 + l4) * 64 + quad*8;
        const u16* rb = Qp + (size_t)(q0b + w*16 + l4) * 64 + quad*8;
        qfa[0] = *(const bf16x8*)ra; qfa[1] = *(const bf16x8*)(ra + 32);
        qfb[0] = *(const bf16x8*)rb; qfb[1] = *(const bf16x8*)(rb + 32);
    }

    f32x4 oa[4] = {}, ob[4] = {};
    float la[4] = {}, lb[4] = {};

    const int srow = tid >> 2;
    const int sc   = (tid & 3) * 16;

    u16x8 kr0, kr1, vr0, vr1; unsigned char pr = 0;
    {
        const u16* kg = Kp + (size_t)srow * 64 + sc;
        kr0 = *(const u16x8*)kg; kr1 = *(const u16x8*)(kg + 8);
        const u16* vg = VTp + (size_t)srow * Tq + sc;
        vr0 = *(const u16x8*)vg; vr1 = *(const u16x8*)(vg + 8);
        if (tid < 64) pr = pad[(size_t)b * Tq + tid];
    }

    const float SC = 0.18033688011112042f;   // log2(e)/sqrt(64)
    const int qra = q0a + w*16 + quad*4;
    const int qrb = q0b + w*16 + quad*4;

    for (int kt = 0; kt <= qb; ++kt) {
        const int k0 = kt * 64;
        const bool actA = (kt <= qa);
        __syncthreads();
        *(u16x8*)&Klds[srow * LSTR + sc]     = kr0;
        *(u16x8*)&Klds[srow * LSTR + sc + 8] = kr1;
        *(u16x8*)&Vtl [srow * LSTR + sc]     = vr0;
        *(u16x8*)&Vtl [srow * LSTR + sc + 8] = vr1;
        if (tid < 64) padl[tid] = pr;
        __syncthreads();
        if (kt < qb) {
            const u16* kg = Kp + (size_t)(k0 + 64 + srow) * 64 + sc;
            kr0 = *(const u16x8*)kg; kr1 = *(const u16x8*)(kg + 8);
            const u16* vg = VTp + (size_t)srow * Tq + k0 + 64 + sc;
            vr0 = *(const u16x8*)vg; vr1 = *(const u16x8*)(vg + 8);
            if (tid < 64) pr = pad[(size_t)b * Tq + k0 + 64 + tid];
        }

        bool pm[4];
#pragma unroll
        for (int n = 0; n < 4; ++n) pm[n] = (padl[n*16 + l4] != 0);

        {
            f32x4 sacc[4] = {};
#pragma unroll
            for (int c = 0; c < 2; ++c)
#pragma unroll
                for (int n = 0; n < 4; ++n) {
                    bf16x8 kf = *(const bf16x8*)&Klds[(n*16 + l4) * LSTR + c*32 + quad*8];
                    sacc[n] = __builtin_amdgcn_mfma_f32_16x16x32_bf16(qfb[c], kf, sacc[n], 0, 0, 0);
                }
#pragma unroll
            for (int r = 0; r < 4; ++r) {
                float rs = 0.f;
#pragma unroll
                for (int n = 0; n < 4; ++n) {
                    const int kgi = k0 + n*16 + l4;
                    const bool msk = (kgi > qrb + r) || pm[n];
                    const float p = msk ? 0.0f : exp2f(sacc[n][r] * SC);
                    rs += p;
                    Pb[(w*16 + quad*4 + r) * LSTR + n*16 + l4] = f2bf(p);
                }
                lb[r] += rs;
            }
        }
        if (actA) {
            f32x4 sacc[4] = {};
#pragma unroll
            for (int c = 0; c < 2; ++c)
#pragma unroll
                for (int n = 0; n < 4; ++n) {
                    bf16x8 kf = *(const bf16x8*)&Klds[(n*16 + l4) * LSTR + c*32 + quad*8];
                    sacc[n] = __builtin_amdgcn_mfma_f32_16x16x32_bf16(qfa[c], kf, sacc[n], 0, 0, 0);
                }
#pragma unroll
            for (int r = 0; r < 4; ++r) {
                float rs = 0.f;
#pragma unroll
                for (int n = 0; n < 4; ++n) {
                    const int kgi = k0 + n*16 + l4;
                    const bool msk = (kgi > qra + r) || pm[n];
                    const float p = msk ? 0.0f : exp2f(sacc[n][r] * SC);
                    rs += p;
                    Pa[(w*16 + quad*4 + r) * LSTR + n*16 + l4] = f2bf(p);
                }
                la[r] += rs;
            }
        }
        __syncthreads();

#pragma unroll
        for (int c = 0; c < 2; ++c) {
            bf16x8 pfb = *(const bf16x8*)&Pb[(w*16 + l4) * LSTR + c*32 + quad*8];
#pragma unroll
            for (int t = 0; t < 4; ++t) {
                bf16x8 vf = *(const bf16x8*)&Vtl[(t*16 + l4) * LSTR + c*32 + quad*8];
                ob[t] = __builtin_amdgcn_mfma_f32_16x16x32_bf16(pfb, vf, ob[t], 0, 0, 0);
            }
        }
        if (actA) {
#pragma unroll
            for (int c = 0; c < 2; ++c) {
                bf16x8 pfa = *(const bf16x8*)&Pa[(w*16 + l4) * LSTR + c*32 + quad*8];
#pragma unroll
                for (int t = 0; t < 4; ++t) {
                    bf16x8 vf = *(const bf16x8*)&Vtl[(t*16 + l4) * LSTR + c*32 + quad*8];
                    oa[t] = __builtin_amdgcn_mfma_f32_16x16x32_bf16(pfa, vf, oa[t], 0, 0, 0);
                }
            }
        }
    }

#pragma unroll
    for (int r = 0; r < 4; ++r) {
#pragma unroll
        for (int s = 1; s < 16; s <<= 1) {
            la[r] += __shfl_xor(la[r], s);
            lb[r] += __shfl_xor(lb[r], s);
        }
    }
#pragma unroll
    for (int r = 0; r < 4; ++r) {
        const float ia = 1.0f / la[r], ib = 1.0f / lb[r];
        u16* ya = Y + (size_t)(b * Tq + (q0a + w*16 + quad*4 + r)) * DM + h * 64;
        u16* yb = Y + (size_t)(b * Tq + (q0b + w*16 + quad*4 + r)) * DM + h * 64;
#pragma unroll
        for (int t = 0; t < 4; ++t) {
            ya[t*16 + l4] = f2bf(oa[t][r] * ia);
            yb[t*16 + l4] = f2bf(ob[t][r] * ib);
        }
    }
}

// ---------------------------------------------------------------------------
extern "C" void kernel_launch(void* const* d_in, const int* in_sizes, int n_in,
                              void* d_out, int out_size, void* d_ws, size_t ws_size,
                              hipStream_t stream) {
    const void* x  = d_in[0];
    const unsigned char* pad = (const unsigned char*)d_in[1];
    const void* Wq = d_in[2];
    const void* bq = d_in[3];
    const void* Wk = d_in[4];
    const void* bk = d_in[5];
    const void* Wv = d_in[6];
    const void* bv = d_in[7];
    const void* Wo = d_in[8];
    const void* bo = d_in[9];
    const u16* xs = (const u16*)x;

    const size_t NEL = (size_t)8192 * 1024;
    const size_t WEL = (size_t)1024 * 1024;

    int* flag   = (int*)d_ws;
    u16* base16 = (u16*)((char*)d_ws + 256);
    u16* xc     = base16;                          // canonical x; reused as Yb
    u16* Wc     = base16 + NEL;                    // Wq,Wk,Wv,Wo
    float* bf_  = (float*)(base16 + NEL + 4*WEL);  // 4 x 1024 fp32 biases
    u16* Qb     = (u16*)(bf_ + 4096);
    u16* Kb     = Qb + NEL;
    u16* Vb     = Kb + NEL;
    u16* VT     = Vb + NEL;                        // (B,H,64,T)
    u16* Yb     = xc;

    cvt_tensor<<<dim3((int)(NEL/2048)), 256, 0, stream>>>(x, xc, (int)NEL, xs, flag, 1);
    cvt_w4b<<<dim3(512, 4), 256, 0, stream>>>(Wq, Wk, Wv, Wo, bq, bk, bv, bo, Wc, bf_, xs);

    gemm_bt<<<dim3(64, 24), 256, 0, stream>>>(xc, Wc, Wc + WEL, Wc + 2*WEL,
                                              bf_, bf_ + 1024, bf_ + 2048,
                                              Qb, Kb, Vb, flag, 0);
    vtrans<<<dim3(32, 64), 256, 0, stream>>>(Vb, VT);
    attn2<<<dim3(64, 16), 256, 0, stream>>>(Qb, Kb, VT, pad, Yb);
    gemm_bt<<<dim3(64, 8), 256, 0, stream>>>(Yb, Wc + 3*WEL, Wc + 3*WEL, Wc + 3*WEL,
                                             bf_ + 3072, bf_ + 3072, bf_ + 3072,
                                             (u16*)d_out, nullptr, nullptr, flag, 1);
}